// Round 4
// baseline (28721.277 us; speedup 1.0000x reference)
//
#include <hip/hip_runtime.h>
#include <math.h>

// Problem constants
#define B 128
#define T 1024
#define E 256
#define H 512

// ws layout (floats):
//   h_buf : 2 * [512][128]  (double-buffered, [unit][batch])
//   c_buf : [512][128]
//   last_h: [512][128]
//   last_c: [512][128]
//   Lsteps: 128 ints
#define HBUF_OFF   0
#define CBUF_OFF   (2*65536)
#define LASTH_OFF  (3*65536)
#define LASTC_OFF  (4*65536)
#define LSTEP_OFF  (5*65536)

// Accurate transcendentals (OCML expf/tanhf; no -ffast-math in harness build).
__device__ __forceinline__ float sigm_f(float x) {
    return 1.f / (1.f + expf(-x));
}
__device__ __forceinline__ float tanh_f(float x) {
    return tanhf(x);
}
__device__ __forceinline__ void fma4(float4& a, const float4 w, const float4 x) {
    a.x = fmaf(w.x, x.x, a.x);
    a.y = fmaf(w.y, x.y, a.y);
    a.z = fmaf(w.z, x.z, a.z);
    a.w = fmaf(w.w, x.w, a.w);
}

// ---------------------------------------------------------------------------
// init: per-row length + transpose h0/c0 into [unit][batch] layout
// grid 128 x 256
__global__ __launch_bounds__(256) void init_kernel(
    const int* __restrict__ tokens, const float* __restrict__ h0,
    const float* __restrict__ c0, float* __restrict__ ws) {
    const int b = blockIdx.x, tid = threadIdx.x;
    float* h_buf = ws + HBUF_OFF;
    float* c_buf = ws + CBUF_OFF;
    int*   Lsteps = (int*)(ws + LSTEP_OFF);

    for (int u = tid; u < H; u += 256) {
        h_buf[u * B + b] = h0[b * H + u];
        c_buf[u * B + b] = c0[b * H + u];
    }
    __shared__ int s_fz;
    if (tid == 0) s_fz = T;
    __syncthreads();
    int fz = T;
    for (int tt = tid; tt < T; tt += 256)
        if (tokens[b * T + tt] == 0) fz = min(fz, tt);
    atomicMin(&s_fz, fz);
    __syncthreads();
    if (tid == 0) {
        int f = s_fz;
        // steps = first_zero (>=1), or T if no zero / wrap (first_zero==0)
        Lsteps[b] = (f == 0 || f == T) ? T : f;
    }
}

// ---------------------------------------------------------------------------
// one LSTM time step
// grid 256 x 256; block: group g = bid>>5 (16 batch rows), member m = bid&31
// (16 h-units). thread: ul = tid>>4 (unit), b = tid&15 (batch lane)
__global__ __launch_bounds__(256) void step_kernel(
    const int* __restrict__ tokens, const float* __restrict__ emb,
    const float* __restrict__ W_ih, const float* __restrict__ b_ih,
    const float* __restrict__ W_hh, const float* __restrict__ b_hh,
    const float* __restrict__ hprev, float* __restrict__ hnext,
    float* __restrict__ c_buf, float* __restrict__ last_h,
    float* __restrict__ last_c, const int* __restrict__ Lsteps, int t) {
    const int tid = threadIdx.x, bid = blockIdx.x;
    const int g = bid >> 5, m = bid & 31;

    // group early-exit (uniform, scalarizes)
    int Tg = 0;
#pragma unroll
    for (int i = 0; i < 16; ++i) Tg = max(Tg, Lsteps[g * 16 + i]);
    if (t >= Tg) return;

    __shared__ float xh[16 * 772];  // [b][k], k-padded 768->772 (16B-aligned rows)

    // stage x = emb[token] : 16 rows x 256 floats
    {
        const int b = tid >> 4, kq = tid & 15;
        const int tok = tokens[(g * 16 + b) * T + t];
        const float4* er = (const float4*)emb + (size_t)tok * 64;
        float4* dst = (float4*)&xh[b * 772];
#pragma unroll
        for (int i = 0; i < 4; ++i) dst[kq + 16 * i] = er[kq + 16 * i];
    }
    // stage h : xh[b][256+u] = hprev[u][g*16 + b]
    // R4 FIX: the float4 column index must include the group offset g*4
    // (R1-R3 read batch rows 0..15 for EVERY group -> 7/8 of rows wrong).
    {
        const int bq = tid & 3, uu = tid >> 2;
        const float4* hp4 = (const float4*)hprev;
#pragma unroll
        for (int j = 0; j < 8; ++j) {
            const int u = uu + 64 * j;
            float4 hv = hp4[u * 32 + g * 4 + bq];
            float* dst = &xh[(4 * bq) * 772 + 256 + u];
            dst[0] = hv.x; dst[772] = hv.y; dst[1544] = hv.z; dst[2316] = hv.w;
        }
    }
    __syncthreads();

    const int ul = tid >> 4, b = tid & 15;
    const int unit = m * 16 + ul;
    const int bg = g * 16 + b;

    const float4* xb = (const float4*)&xh[b * 772];
    const float4* Wi = (const float4*)W_ih;
    const float4* Wh = (const float4*)W_hh;
    const float4* wr0 = Wi + (size_t)(unit) * 64;
    const float4* wr1 = Wi + (size_t)(H + unit) * 64;
    const float4* wr2 = Wi + (size_t)(2 * H + unit) * 64;
    const float4* wr3 = Wi + (size_t)(3 * H + unit) * 64;

    float4 s0 = {0, 0, 0, 0}, s1 = {0, 0, 0, 0}, s2 = {0, 0, 0, 0}, s3 = {0, 0, 0, 0};
#pragma unroll 4
    for (int kq = 0; kq < 64; ++kq) {
        const float4 x = xb[kq];
        fma4(s0, wr0[kq], x);
        fma4(s1, wr1[kq], x);
        fma4(s2, wr2[kq], x);
        fma4(s3, wr3[kq], x);
    }
    const float4* vr0 = Wh + (size_t)(unit) * 128;
    const float4* vr1 = Wh + (size_t)(H + unit) * 128;
    const float4* vr2 = Wh + (size_t)(2 * H + unit) * 128;
    const float4* vr3 = Wh + (size_t)(3 * H + unit) * 128;
    const float4* xb2 = xb + 64;
#pragma unroll 4
    for (int kq = 0; kq < 128; ++kq) {
        const float4 x = xb2[kq];
        fma4(s0, vr0[kq], x);
        fma4(s1, vr1[kq], x);
        fma4(s2, vr2[kq], x);
        fma4(s3, vr3[kq], x);
    }

    const float ai = s0.x + s0.y + s0.z + s0.w + b_ih[unit] + b_hh[unit];
    const float af = s1.x + s1.y + s1.z + s1.w + b_ih[H + unit] + b_hh[H + unit];
    const float ag = s2.x + s2.y + s2.z + s2.w + b_ih[2 * H + unit] + b_hh[2 * H + unit];
    const float ao = s3.x + s3.y + s3.z + s3.w + b_ih[3 * H + unit] + b_hh[3 * H + unit];

    const float ig = sigm_f(ai);
    const float fg = sigm_f(af);
    const float gv = tanh_f(ag);
    const float og = sigm_f(ao);

    const int idx = unit * B + bg;
    const float c_old = c_buf[idx];
    const float c_new = fg * c_old + ig * gv;
    const float h_new = og * tanh_f(c_new);
    c_buf[idx] = c_new;
    hnext[idx] = h_new;
    if (t == Lsteps[bg] - 1) {
        last_h[idx] = h_new;
        last_c[idx] = c_new;
    }
}

// ---------------------------------------------------------------------------
// final: y = [h;c] @ W_proj^T + b_proj ; out = y @ W_out^T + b_out
// grid 128 x 256 (one block per batch row)
__global__ __launch_bounds__(256) void final_kernel(
    const float* __restrict__ ws_ro, const float* __restrict__ W_proj,
    const float* __restrict__ b_proj, const float* __restrict__ W_out,
    const float* __restrict__ b_out, float* __restrict__ out) {
    const int bg = blockIdx.x, tid = threadIdx.x;
    const float* last_h = ws_ro + LASTH_OFF;
    const float* last_c = ws_ro + LASTC_OFF;

    __shared__ float s_hc[2 * H];
    __shared__ float s_y[H];
    for (int u = tid; u < H; u += 256) {
        s_hc[u]     = last_h[u * B + bg];
        s_hc[H + u] = last_c[u * B + bg];
    }
    __syncthreads();

    const float4* hc4 = (const float4*)s_hc;
    const float4* Wp4 = (const float4*)W_proj;
#pragma unroll
    for (int jj = 0; jj < 2; ++jj) {
        const int j = tid + jj * 256;
        const float4* wr = Wp4 + (size_t)j * 256;
        float4 acc = {0, 0, 0, 0};
#pragma unroll 4
        for (int kq = 0; kq < 256; ++kq) fma4(acc, wr[kq], hc4[kq]);
        s_y[j] = acc.x + acc.y + acc.z + acc.w + b_proj[j];
    }
    __syncthreads();

    if (tid < 64) {
        float p0 = 0.f, p1 = 0.f;
        for (int j = tid; j < H; j += 64) {
            const float y = s_y[j];
            p0 = fmaf(y, W_out[j], p0);
            p1 = fmaf(y, W_out[H + j], p1);
        }
#pragma unroll
        for (int off = 32; off; off >>= 1) {
            p0 += __shfl_down(p0, off);
            p1 += __shfl_down(p1, off);
        }
        if (tid == 0) {
            out[bg * 2 + 0] = p0 + b_out[0];
            out[bg * 2 + 1] = p1 + b_out[1];
        }
    }
}

// ---------------------------------------------------------------------------
extern "C" void kernel_launch(void* const* d_in, const int* in_sizes, int n_in,
                              void* d_out, int out_size, void* d_ws, size_t ws_size,
                              hipStream_t stream) {
    const int*   tokens = (const int*)d_in[0];
    const float* emb    = (const float*)d_in[1];
    const float* W_ih   = (const float*)d_in[2];
    const float* b_ih   = (const float*)d_in[3];
    const float* W_hh   = (const float*)d_in[4];
    const float* b_hh   = (const float*)d_in[5];
    const float* W_proj = (const float*)d_in[6];
    const float* b_proj = (const float*)d_in[7];
    const float* W_out  = (const float*)d_in[8];
    const float* b_out  = (const float*)d_in[9];
    const float* h0     = (const float*)d_in[10];
    const float* c0     = (const float*)d_in[11];
    float* out = (float*)d_out;
    float* ws  = (float*)d_ws;

    float* h_buf  = ws + HBUF_OFF;
    float* c_buf  = ws + CBUF_OFF;
    int*   Lsteps = (int*)(ws + LSTEP_OFF);
    float* last_h = ws + LASTH_OFF;
    float* last_c = ws + LASTC_OFF;

    hipLaunchKernelGGL(init_kernel, dim3(B), dim3(256), 0, stream,
                       tokens, h0, c0, ws);

    for (int t = 0; t < T; ++t) {
        const float* hprev = h_buf + (t & 1) * (H * B);
        float*       hnext = h_buf + ((t + 1) & 1) * (H * B);
        hipLaunchKernelGGL(step_kernel, dim3(256), dim3(256), 0, stream,
                           tokens, emb, W_ih, b_ih, W_hh, b_hh,
                           hprev, hnext, c_buf, last_h, last_c, Lsteps, t);
    }

    hipLaunchKernelGGL(final_kernel, dim3(B), dim3(256), 0, stream,
                       ws, W_proj, b_proj, W_out, b_out, out);
}

// Round 5
// 25733.109 us; speedup vs baseline: 1.1161x; 1.1161x over previous
//
#include <hip/hip_runtime.h>
#include <math.h>

// Problem constants
#define B 128
#define T 1024
#define E 256
#define H 512

// ws layout (floats):
//   h_buf : 2 * [512][128]  (double-buffered, [unit][batch])
//   c_buf : [512][128]
//   last_h: [512][128]
//   last_c: [512][128]
//   Lsteps: 128 ints
#define HBUF_OFF   0
#define CBUF_OFF   (2*65536)
#define LASTH_OFF  (3*65536)
#define LASTC_OFF  (4*65536)
#define LSTEP_OFF  (5*65536)

// Accurate transcendentals (OCML expf/tanhf): R4 matched np bit-exact.
__device__ __forceinline__ float sigm_f(float x) {
    return 1.f / (1.f + expf(-x));
}
__device__ __forceinline__ float tanh_f(float x) {
    return tanhf(x);
}
__device__ __forceinline__ void fma4(float4& a, const float4 w, const float4 x) {
    a.x = fmaf(w.x, x.x, a.x);
    a.y = fmaf(w.y, x.y, a.y);
    a.z = fmaf(w.z, x.z, a.z);
    a.w = fmaf(w.w, x.w, a.w);
}

// ---------------------------------------------------------------------------
// init: per-row length + transpose h0/c0 into [unit][batch] layout
// grid 128 x 256
__global__ __launch_bounds__(256) void init_kernel(
    const int* __restrict__ tokens, const float* __restrict__ h0,
    const float* __restrict__ c0, float* __restrict__ ws) {
    const int b = blockIdx.x, tid = threadIdx.x;
    float* h_buf = ws + HBUF_OFF;
    float* c_buf = ws + CBUF_OFF;
    int*   Lsteps = (int*)(ws + LSTEP_OFF);

    for (int u = tid; u < H; u += 256) {
        h_buf[u * B + b] = h0[b * H + u];
        c_buf[u * B + b] = c0[b * H + u];
    }
    __shared__ int s_fz;
    if (tid == 0) s_fz = T;
    __syncthreads();
    int fz = T;
    for (int tt = tid; tt < T; tt += 256)
        if (tokens[b * T + tt] == 0) fz = min(fz, tt);
    atomicMin(&s_fz, fz);
    __syncthreads();
    if (tid == 0) {
        int f = s_fz;
        Lsteps[b] = (f == 0 || f == T) ? T : f;
    }
}

// ---------------------------------------------------------------------------
// one LSTM time step, K-split for occupancy.
// grid 256 x 1024; block (g,m): g=bid>>5 (16 batch rows), m=bid&31 (16 units).
// thread: kq=tid>>8 (K-quarter), ul=(tid>>4)&15, b=tid&15.
// Each thread: partial dot over 192 K-elems for 4 gate rows of `unit`;
// partials reduced via LDS; tid<256 finish gates + elementwise.
__global__ __launch_bounds__(1024) void step_kernel(
    const int* __restrict__ tokens, const float* __restrict__ emb,
    const float* __restrict__ W_ih, const float* __restrict__ b_ih,
    const float* __restrict__ W_hh, const float* __restrict__ b_hh,
    const float* __restrict__ hprev, float* __restrict__ hnext,
    float* __restrict__ c_buf, float* __restrict__ last_h,
    float* __restrict__ last_c, const int* __restrict__ Lsteps, int t) {
    const int tid = threadIdx.x, bid = blockIdx.x;
    const int g = bid >> 5, m = bid & 31;

    // group early-exit (uniform)
    int Tg = 0;
#pragma unroll
    for (int i = 0; i < 16; ++i) Tg = max(Tg, Lsteps[g * 16 + i]);
    if (t >= Tg) return;

    __shared__ float  xh[16 * 772];       // [b][k], row-padded 768->772
    __shared__ float4 part[4 * 256];      // [kq][ul*16+b] = {ai,af,ag,ao}

    // stage x = emb[token]: 16 rows x 64 float4 -> 1024 float4, 1 per thread
    {
        const int b = tid >> 6, kq4 = tid & 63;
        const int tok = tokens[(g * 16 + b) * T + t];
        ((float4*)&xh[b * 772])[kq4] =
            ((const float4*)emb)[(size_t)tok * 64 + kq4];
    }
    // stage h: xh[b][256+u] = hprev[u][g*16+b]; 2048 float4 reads, 2/thread
    {
        const float4* hp4 = (const float4*)hprev;
#pragma unroll
        for (int j = 0; j < 2; ++j) {
            const int idx = tid + j * 1024;        // [0,2048)
            const int u = idx >> 2, bq = idx & 3;
            float4 hv = hp4[u * 32 + g * 4 + bq];  // batches g*16+4bq..+3
            float* dst = &xh[(4 * bq) * 772 + 256 + u];
            dst[0] = hv.x; dst[772] = hv.y; dst[1544] = hv.z; dst[2316] = hv.w;
        }
    }
    __syncthreads();

    const int kq = tid >> 8, ul = (tid >> 4) & 15, b = tid & 15;
    const int unit = m * 16 + ul;

    const float4* xb = (const float4*)&xh[b * 772];
    const float4* Wi = (const float4*)W_ih;
    const float4* Wh = (const float4*)W_hh;
    const float4* wr0 = Wi + (size_t)(unit) * 64;
    const float4* wr1 = Wi + (size_t)(H + unit) * 64;
    const float4* wr2 = Wi + (size_t)(2 * H + unit) * 64;
    const float4* wr3 = Wi + (size_t)(3 * H + unit) * 64;
    const float4* vr0 = Wh + (size_t)(unit) * 128;
    const float4* vr1 = Wh + (size_t)(H + unit) * 128;
    const float4* vr2 = Wh + (size_t)(2 * H + unit) * 128;
    const float4* vr3 = Wh + (size_t)(3 * H + unit) * 128;

    // K-quarter bounds in float4 units (48 f4 per quarter; x=f4 0..63, h=64..191)
    const int k4lo = kq * 48, k4hi = k4lo + 48;
    const int xlo = min(k4lo, 64), xhi = min(k4hi, 64);
    const int hlo = max(k4lo, 64) - 64, hhi = max(k4hi, 64) - 64;

    float4 s0 = {0, 0, 0, 0}, s1 = {0, 0, 0, 0}, s2 = {0, 0, 0, 0}, s3 = {0, 0, 0, 0};
#pragma unroll 4
    for (int k4 = xlo; k4 < xhi; ++k4) {
        const float4 x = xb[k4];
        fma4(s0, wr0[k4], x);
        fma4(s1, wr1[k4], x);
        fma4(s2, wr2[k4], x);
        fma4(s3, wr3[k4], x);
    }
#pragma unroll 4
    for (int k4 = hlo; k4 < hhi; ++k4) {
        const float4 x = xb[64 + k4];
        fma4(s0, vr0[k4], x);
        fma4(s1, vr1[k4], x);
        fma4(s2, vr2[k4], x);
        fma4(s3, vr3[k4], x);
    }

    float4 p;
    p.x = s0.x + s0.y + s0.z + s0.w;
    p.y = s1.x + s1.y + s1.z + s1.w;
    p.z = s2.x + s2.y + s2.z + s2.w;
    p.w = s3.x + s3.y + s3.z + s3.w;
    part[kq * 256 + (ul * 16 + b)] = p;
    __syncthreads();

    if (tid < 256) {
        const int ul2 = tid >> 4, b2 = tid & 15;
        const int unit2 = m * 16 + ul2;
        const int bg = g * 16 + b2;
        float4 q0 = part[tid], q1 = part[256 + tid];
        float4 q2 = part[512 + tid], q3 = part[768 + tid];
        const float ai = (q0.x + q1.x) + (q2.x + q3.x) + b_ih[unit2] + b_hh[unit2];
        const float af = (q0.y + q1.y) + (q2.y + q3.y) + b_ih[H + unit2] + b_hh[H + unit2];
        const float ag = (q0.z + q1.z) + (q2.z + q3.z) + b_ih[2 * H + unit2] + b_hh[2 * H + unit2];
        const float ao = (q0.w + q1.w) + (q2.w + q3.w) + b_ih[3 * H + unit2] + b_hh[3 * H + unit2];

        const float ig = sigm_f(ai);
        const float fg = sigm_f(af);
        const float gv = tanh_f(ag);
        const float og = sigm_f(ao);

        const int idx = unit2 * B + bg;
        const float c_old = c_buf[idx];
        const float c_new = fg * c_old + ig * gv;
        const float h_new = og * tanh_f(c_new);
        c_buf[idx] = c_new;
        hnext[idx] = h_new;
        if (t == Lsteps[bg] - 1) {
            last_h[idx] = h_new;
            last_c[idx] = c_new;
        }
    }
}

// ---------------------------------------------------------------------------
// final: y = [h;c] @ W_proj^T + b_proj ; out = y @ W_out^T + b_out
// grid 128 x 256
__global__ __launch_bounds__(256) void final_kernel(
    const float* __restrict__ ws_ro, const float* __restrict__ W_proj,
    const float* __restrict__ b_proj, const float* __restrict__ W_out,
    const float* __restrict__ b_out, float* __restrict__ out) {
    const int bg = blockIdx.x, tid = threadIdx.x;
    const float* last_h = ws_ro + LASTH_OFF;
    const float* last_c = ws_ro + LASTC_OFF;

    __shared__ float s_hc[2 * H];
    __shared__ float s_y[H];
    for (int u = tid; u < H; u += 256) {
        s_hc[u]     = last_h[u * B + bg];
        s_hc[H + u] = last_c[u * B + bg];
    }
    __syncthreads();

    const float4* hc4 = (const float4*)s_hc;
    const float4* Wp4 = (const float4*)W_proj;
#pragma unroll
    for (int jj = 0; jj < 2; ++jj) {
        const int j = tid + jj * 256;
        const float4* wr = Wp4 + (size_t)j * 256;
        float4 acc = {0, 0, 0, 0};
#pragma unroll 4
        for (int kq = 0; kq < 256; ++kq) fma4(acc, wr[kq], hc4[kq]);
        s_y[j] = acc.x + acc.y + acc.z + acc.w + b_proj[j];
    }
    __syncthreads();

    if (tid < 64) {
        float p0 = 0.f, p1 = 0.f;
        for (int j = tid; j < H; j += 64) {
            const float y = s_y[j];
            p0 = fmaf(y, W_out[j], p0);
            p1 = fmaf(y, W_out[H + j], p1);
        }
#pragma unroll
        for (int off = 32; off; off >>= 1) {
            p0 += __shfl_down(p0, off);
            p1 += __shfl_down(p1, off);
        }
        if (tid == 0) {
            out[bg * 2 + 0] = p0 + b_out[0];
            out[bg * 2 + 1] = p1 + b_out[1];
        }
    }
}

// ---------------------------------------------------------------------------
extern "C" void kernel_launch(void* const* d_in, const int* in_sizes, int n_in,
                              void* d_out, int out_size, void* d_ws, size_t ws_size,
                              hipStream_t stream) {
    const int*   tokens = (const int*)d_in[0];
    const float* emb    = (const float*)d_in[1];
    const float* W_ih   = (const float*)d_in[2];
    const float* b_ih   = (const float*)d_in[3];
    const float* W_hh   = (const float*)d_in[4];
    const float* b_hh   = (const float*)d_in[5];
    const float* W_proj = (const float*)d_in[6];
    const float* b_proj = (const float*)d_in[7];
    const float* W_out  = (const float*)d_in[8];
    const float* b_out  = (const float*)d_in[9];
    const float* h0     = (const float*)d_in[10];
    const float* c0     = (const float*)d_in[11];
    float* out = (float*)d_out;
    float* ws  = (float*)d_ws;

    float* h_buf  = ws + HBUF_OFF;
    float* c_buf  = ws + CBUF_OFF;
    float* last_h = ws + LASTH_OFF;
    float* last_c = ws + LASTC_OFF;
    int*   Lsteps = (int*)(ws + LSTEP_OFF);

    hipLaunchKernelGGL(init_kernel, dim3(B), dim3(256), 0, stream,
                       tokens, h0, c0, ws);

    for (int t = 0; t < T; ++t) {
        const float* hprev = h_buf + (t & 1) * (H * B);
        float*       hnext = h_buf + ((t + 1) & 1) * (H * B);
        hipLaunchKernelGGL(step_kernel, dim3(256), dim3(1024), 0, stream,
                           tokens, emb, W_ih, b_ih, W_hh, b_hh,
                           hprev, hnext, c_buf, last_h, last_c, Lsteps, t);
    }

    hipLaunchKernelGGL(final_kernel, dim3(B), dim3(256), 0, stream,
                       ws, W_proj, b_proj, W_out, b_out, out);
}